// Round 2
// baseline (102.349 us; speedup 1.0000x reference)
//
#include <hip/hip_runtime.h>

#define N 8192
#define F 256
#define D 64

// ---------------------------------------------------------------------------
// K1: sf = seq@W0 (fp32), f1 = sf@w1+b1, f2 = sf@w2+b2
// 256 blocks x 256 thr, 32 rows/block. W0 (64KB) + padded seq rows (33KB) in LDS.
// thread: cg=t&15 owns 4 cols, rg=t>>4 owns 2 rows.
// ---------------------------------------------------------------------------
__global__ __launch_bounds__(256) void k_proj(
    const float* __restrict__ seq, const float* __restrict__ W0,
    const float* __restrict__ w1, const float* __restrict__ b1,
    const float* __restrict__ w2, const float* __restrict__ b2,
    float* __restrict__ sf, float* __restrict__ f1, float* __restrict__ f2) {
  __shared__ __align__(16) float lw0[F * D];      // 64 KB, [256][64]
  __shared__ __align__(16) float srow[32 * 260];  // 33.3 KB, pad 260 -> conflict-free
  const int t = threadIdx.x;
  {
    const float4* g = (const float4*)W0;
    float4* l = (float4*)lw0;
    #pragma unroll
    for (int i = 0; i < 16; ++i) l[t + i * 256] = g[t + i * 256];
  }
  const int base = blockIdx.x * 32;
  {
    const float4* g = (const float4*)(seq + (size_t)base * F);
    #pragma unroll
    for (int i = 0; i < 8; ++i) {
      int idx = t + i * 256;              // float4 index within 32x256 tile
      int r = idx >> 6, c4 = idx & 63;
      *(float4*)(srow + r * 260 + c4 * 4) = g[idx];
    }
  }
  __syncthreads();
  const int cg = t & 15, rg = t >> 4;
  const int r0 = rg * 2;
  float acc0[4] = {0.f, 0.f, 0.f, 0.f}, acc1[4] = {0.f, 0.f, 0.f, 0.f};
  const float* s0 = srow + r0 * 260;
  const float* s1 = s0 + 260;
  const float* wb = lw0 + cg * 4;
  #pragma unroll 4
  for (int k = 0; k < F; k += 4) {
    float a0[4], a1[4];
    *(float4*)a0 = *(const float4*)(s0 + k);
    *(float4*)a1 = *(const float4*)(s1 + k);
    #pragma unroll
    for (int m = 0; m < 4; ++m) {
      float4 w = *(const float4*)(wb + (k + m) * D);
      acc0[0] += a0[m] * w.x; acc0[1] += a0[m] * w.y;
      acc0[2] += a0[m] * w.z; acc0[3] += a0[m] * w.w;
      acc1[0] += a1[m] * w.x; acc1[1] += a1[m] * w.y;
      acc1[2] += a1[m] * w.z; acc1[3] += a1[m] * w.w;
    }
  }
  const int row0 = base + r0, row1 = row0 + 1;
  *(float4*)(sf + (size_t)row0 * D + cg * 4) = make_float4(acc0[0], acc0[1], acc0[2], acc0[3]);
  *(float4*)(sf + (size_t)row1 * D + cg * 4) = make_float4(acc1[0], acc1[1], acc1[2], acc1[3]);
  float w1v[4], w2v[4];
  *(float4*)w1v = *(const float4*)(w1 + cg * 4);
  *(float4*)w2v = *(const float4*)(w2 + cg * 4);
  float p0 = acc0[0]*w1v[0] + acc0[1]*w1v[1] + acc0[2]*w1v[2] + acc0[3]*w1v[3];
  float q0 = acc0[0]*w2v[0] + acc0[1]*w2v[1] + acc0[2]*w2v[2] + acc0[3]*w2v[3];
  float p1 = acc1[0]*w1v[0] + acc1[1]*w1v[1] + acc1[2]*w1v[2] + acc1[3]*w1v[3];
  float q1 = acc1[0]*w2v[0] + acc1[1]*w2v[1] + acc1[2]*w2v[2] + acc1[3]*w2v[3];
  #pragma unroll
  for (int d = 1; d < 16; d <<= 1) {
    p0 += __shfl_xor(p0, d, 64); q0 += __shfl_xor(q0, d, 64);
    p1 += __shfl_xor(p1, d, 64); q1 += __shfl_xor(q1, d, 64);
  }
  if (cg == 0) {
    f1[row0] = p0 + b1[0]; f2[row0] = q0 + b2[0];
    f1[row1] = p1 + b1[0]; f2[row1] = q1 + b2[0];
  }
}

// ---------------------------------------------------------------------------
// K2 (fused rank+scatter, NO atomics, NO memset):
// 256 blocks. Each block stages all f2 in LDS (32 KB), computes exact ranks
// for its 32 j's (4 j per lane-quad-group, 32 lanes per j-quad, k interleaved
// k=kk*32+ks for stride-1 conflict-free LDS), shfl-reduces, then scatters
// f2s/us/u2s/idxs at the rank position. rank[j] = #{k: f2[k]<f2[j] or
// (== and k<j)} is an exact permutation -> deterministic scatter.
// ---------------------------------------------------------------------------
__global__ __launch_bounds__(256) void k_rankscatter(
    const float* __restrict__ f2,
    float* __restrict__ f2s, float* __restrict__ us, float* __restrict__ u2s,
    int* __restrict__ idxs) {
  __shared__ float lf2[N];  // 32 KB
  const int t = threadIdx.x;
  {
    const float4* g = (const float4*)f2;
    float4* l = (float4*)lf2;
    #pragma unroll
    for (int i = 0; i < 8; ++i) l[t + i * 256] = g[t + i * 256];
  }
  __syncthreads();
  const int qg = t >> 5;   // 0..7: which j-quad this thread helps with
  const int ks = t & 31;   // k-slice lane
  const int j0 = blockIdx.x * 32 + qg * 4;
  float fj0 = lf2[j0 + 0], fj1 = lf2[j0 + 1], fj2 = lf2[j0 + 2], fj3 = lf2[j0 + 3];
  int c0 = 0, c1 = 0, c2 = 0, c3 = 0;
  #pragma unroll 8
  for (int kk = 0; kk < 256; ++kk) {
    const int k = kk * 32 + ks;          // stride-1 across lanes -> no conflicts
    const float v = lf2[k];
    c0 += (v < fj0 || (v == fj0 && k < j0 + 0)) ? 1 : 0;
    c1 += (v < fj1 || (v == fj1 && k < j0 + 1)) ? 1 : 0;
    c2 += (v < fj2 || (v == fj2 && k < j0 + 2)) ? 1 : 0;
    c3 += (v < fj3 || (v == fj3 && k < j0 + 3)) ? 1 : 0;
  }
  #pragma unroll
  for (int m = 1; m < 32; m <<= 1) {
    c0 += __shfl_xor(c0, m, 64);
    c1 += __shfl_xor(c1, m, 64);
    c2 += __shfl_xor(c2, m, 64);
    c3 += __shfl_xor(c3, m, 64);
  }
  if (ks == 0) {
    const int   cs[4] = {c0, c1, c2, c3};
    const float fv[4] = {fj0, fj1, fj2, fj3};
    #pragma unroll
    for (int i = 0; i < 4; ++i) {
      const int r = cs[i];
      const float v = fv[i];
      f2s[r]  = v;
      us[r]   = expf(v);
      u2s[r]  = expf(0.2f * v);
      idxs[r] = j0 + i;
    }
  }
}

// ---------------------------------------------------------------------------
// K4: cumulative sums over sorted positions (double accumulation).
//  block c<64   : prefNv[k][c] = sum_{pos<k} u2*sf[idx][c]   (k=0..N)
//  block c==64  : prefNs[k]    = sum_{pos<k} u2
//  block 65+c   : sufPv[k][c]  = sum_{pos>=k} u*sf[idx][c]
//  block 129    : sufPs[k]     = sum_{pos>=k} u
// 512 thr, 16 chunks, wave-shfl scan + cross-wave LDS, next-chunk prefetch.
// ---------------------------------------------------------------------------
__global__ __launch_bounds__(512) void k_scan(
    const float* __restrict__ us, const float* __restrict__ u2s,
    const int* __restrict__ idxs, const float* __restrict__ sf,
    float* __restrict__ prefNv, float* __restrict__ prefNs,
    float* __restrict__ sufPv, float* __restrict__ sufPs) {
  const int t = threadIdx.x;
  const int comp = blockIdx.x;           // 0..129
  const bool pref = comp < 65;
  const int c = pref ? comp : comp - 65; // 64 == scalar
  __shared__ double wtot[8];
  const int wid = t >> 6, lane = t & 63;
  double run = 0.0;

  if (pref) {
    if (t == 0) { if (c < 64) prefNv[c] = 0.f; else prefNs[0] = 0.f; }
    int pos = t;
    double v = (c < 64)
        ? (double)u2s[pos] * (double)sf[(size_t)idxs[pos] * D + c]
        : (double)u2s[pos];
    for (int ch = 0; ch < 16; ++ch) {
      double vn = 0.0;
      if (ch + 1 < 16) {
        int p2 = (ch + 1) * 512 + t;
        vn = (c < 64) ? (double)u2s[p2] * (double)sf[(size_t)idxs[p2] * D + c]
                      : (double)u2s[p2];
      }
      double x = v;
      #pragma unroll
      for (int d = 1; d < 64; d <<= 1) {
        double n = __shfl_up(x, d, 64);
        if (lane >= d) x += n;
      }
      if (lane == 63) wtot[wid] = x;
      __syncthreads();
      double add = run;
      for (int w = 0; w < wid; ++w) add += wtot[w];
      double total = 0.0;
      #pragma unroll
      for (int w = 0; w < 8; ++w) total += wtot[w];
      double incl = x + add;
      int p = ch * 512 + t;
      if (c < 64) prefNv[(size_t)(p + 1) * D + c] = (float)incl;
      else        prefNs[p + 1] = (float)incl;
      run += total;
      __syncthreads();
      v = vn;
    }
  } else {
    if (t == 0) { if (c < 64) sufPv[(size_t)N * D + c] = 0.f; else sufPs[N] = 0.f; }
    int pos = 15 * 512 + t;
    double v = (c < 64)
        ? (double)us[pos] * (double)sf[(size_t)idxs[pos] * D + c]
        : (double)us[pos];
    for (int ch = 15; ch >= 0; --ch) {
      double vn = 0.0;
      if (ch > 0) {
        int p2 = (ch - 1) * 512 + t;
        vn = (c < 64) ? (double)us[p2] * (double)sf[(size_t)idxs[p2] * D + c]
                      : (double)us[p2];
      }
      double x = v;
      #pragma unroll
      for (int d = 1; d < 64; d <<= 1) {
        double n = __shfl_up(x, d, 64);
        if (lane >= d) x += n;
      }
      if (lane == 63) wtot[wid] = x;
      __syncthreads();
      double add = 0.0;
      for (int w = 0; w < wid; ++w) add += wtot[w];
      double total = 0.0;
      #pragma unroll
      for (int w = 0; w < 8; ++w) total += wtot[w];
      double incl = x + add;                  // within-chunk inclusive prefix
      double suff = run + total - (incl - v); // sum over p >= pos
      int p = ch * 512 + t;
      if (c < 64) sufPv[(size_t)p * D + c] = (float)suff;
      else        sufPs[p] = (float)suff;
      run += total;
      __syncthreads();
      v = vn;
    }
  }
}

// ---------------------------------------------------------------------------
// K5: per row i: k = upper_bound(sorted f2, -f1[i]);
//     out = (e^a * sufPv[k] + e^{0.2a} * prefNv[k]) / (scalar analog) + bias
// ---------------------------------------------------------------------------
__global__ __launch_bounds__(256) void k_out(
    const float* __restrict__ f1, const float* __restrict__ f2s,
    const float* __restrict__ prefNv, const float* __restrict__ prefNs,
    const float* __restrict__ sufPv, const float* __restrict__ sufPs,
    const float* __restrict__ bias, float* __restrict__ out) {
  __shared__ float sv[N];  // 32 KB sorted f2
  const int t = threadIdx.x;
  #pragma unroll
  for (int i = 0; i < 32; ++i) sv[t + i * 256] = f2s[t + i * 256];
  __syncthreads();
  const int base = blockIdx.x * 32;
  const int c = t & 63;
  const float bc = bias[c];
  for (int it = 0; it < 8; ++it) {
    const int row = base + it * 4 + (t >> 6);
    const float a = f1[row];
    const float tv = -a;
    int lo = 0, hi = N;
    while (lo < hi) {
      int mid = (lo + hi) >> 1;
      if (sv[mid] <= tv) lo = mid + 1; else hi = mid;
    }
    const int k = lo;  // count of (f2 <= -a) == N-branch size
    const float ea = expf(a), ea2 = expf(0.2f * a);
    const float den = ea * sufPs[k] + ea2 * prefNs[k];
    const float num = ea * sufPv[(size_t)k * D + c] + ea2 * prefNv[(size_t)k * D + c];
    out[(size_t)row * D + c] = num / den + bc;
  }
}

extern "C" void kernel_launch(void* const* d_in, const int* in_sizes, int n_in,
                              void* d_out, int out_size, void* d_ws, size_t ws_size,
                              hipStream_t stream) {
  const float* seq  = (const float*)d_in[0];
  const float* W0   = (const float*)d_in[1];
  const float* w1   = (const float*)d_in[2];
  const float* b1   = (const float*)d_in[3];
  const float* w2   = (const float*)d_in[4];
  const float* b2   = (const float*)d_in[5];
  const float* bias = (const float*)d_in[6];
  float* out = (float*)d_out;

  float* ws   = (float*)d_ws;
  float* sf   = ws;                                    // N*D
  float* f1   = sf + (size_t)N * D;                    // N
  float* f2   = f1 + N;                                // N
  float* f2s  = f2 + N;                                // N
  float* us   = f2s + N;                               // N
  float* u2s  = us + N;                                // N
  int*   idxs = (int*)(u2s + N);                       // N
  float* prefNv = (float*)(idxs + N);                  // (N+1)*D
  float* sufPv  = prefNv + (size_t)(N + 1) * D;        // (N+1)*D
  float* prefNs = sufPv + (size_t)(N + 1) * D;         // N+1
  float* sufPs  = prefNs + (N + 1);                    // N+1
  // total ~6.5 MB of d_ws

  k_proj<<<N / 32, 256, 0, stream>>>(seq, W0, w1, b1, w2, b2, sf, f1, f2);
  k_rankscatter<<<N / 32, 256, 0, stream>>>(f2, f2s, us, u2s, idxs);
  k_scan<<<130, 512, 0, stream>>>(us, u2s, idxs, sf, prefNv, prefNs, sufPv, sufPs);
  k_out<<<N / 32, 256, 0, stream>>>(f1, f2s, prefNv, prefNs, sufPv, sufPs, bias, out);
}

// Round 3
// 54.963 us; speedup vs baseline: 1.8621x; 1.8621x over previous
//
#include <hip/hip_runtime.h>

#define N 8192
#define F 256
#define D 64
#define NCHUNK 256   // scan chunks
#define CHSZ 32      // positions per chunk (8 pg * 4)
#define NCOMP 65     // 64 vector components + 1 scalar

// ---------------------------------------------------------------------------
// K1: sf = seq@W0 (fp32), f1 = sf@w1+b1, f2 = sf@w2+b2   (unchanged control)
// ---------------------------------------------------------------------------
__global__ __launch_bounds__(256) void k_proj(
    const float* __restrict__ seq, const float* __restrict__ W0,
    const float* __restrict__ w1, const float* __restrict__ b1,
    const float* __restrict__ w2, const float* __restrict__ b2,
    float* __restrict__ sf, float* __restrict__ f1, float* __restrict__ f2) {
  __shared__ __align__(16) float lw0[F * D];      // 64 KB
  __shared__ __align__(16) float srow[32 * 260];  // 33.3 KB padded
  const int t = threadIdx.x;
  {
    const float4* g = (const float4*)W0;
    float4* l = (float4*)lw0;
    #pragma unroll
    for (int i = 0; i < 16; ++i) l[t + i * 256] = g[t + i * 256];
  }
  const int base = blockIdx.x * 32;
  {
    const float4* g = (const float4*)(seq + (size_t)base * F);
    #pragma unroll
    for (int i = 0; i < 8; ++i) {
      int idx = t + i * 256;
      int r = idx >> 6, c4 = idx & 63;
      *(float4*)(srow + r * 260 + c4 * 4) = g[idx];
    }
  }
  __syncthreads();
  const int cg = t & 15, rg = t >> 4;
  const int r0 = rg * 2;
  float acc0[4] = {0.f, 0.f, 0.f, 0.f}, acc1[4] = {0.f, 0.f, 0.f, 0.f};
  const float* s0 = srow + r0 * 260;
  const float* s1 = s0 + 260;
  const float* wb = lw0 + cg * 4;
  #pragma unroll 4
  for (int k = 0; k < F; k += 4) {
    float a0[4], a1[4];
    *(float4*)a0 = *(const float4*)(s0 + k);
    *(float4*)a1 = *(const float4*)(s1 + k);
    #pragma unroll
    for (int m = 0; m < 4; ++m) {
      float4 w = *(const float4*)(wb + (k + m) * D);
      acc0[0] += a0[m] * w.x; acc0[1] += a0[m] * w.y;
      acc0[2] += a0[m] * w.z; acc0[3] += a0[m] * w.w;
      acc1[0] += a1[m] * w.x; acc1[1] += a1[m] * w.y;
      acc1[2] += a1[m] * w.z; acc1[3] += a1[m] * w.w;
    }
  }
  const int row0 = base + r0, row1 = row0 + 1;
  *(float4*)(sf + (size_t)row0 * D + cg * 4) = make_float4(acc0[0], acc0[1], acc0[2], acc0[3]);
  *(float4*)(sf + (size_t)row1 * D + cg * 4) = make_float4(acc1[0], acc1[1], acc1[2], acc1[3]);
  float w1v[4], w2v[4];
  *(float4*)w1v = *(const float4*)(w1 + cg * 4);
  *(float4*)w2v = *(const float4*)(w2 + cg * 4);
  float p0 = acc0[0]*w1v[0] + acc0[1]*w1v[1] + acc0[2]*w1v[2] + acc0[3]*w1v[3];
  float q0 = acc0[0]*w2v[0] + acc0[1]*w2v[1] + acc0[2]*w2v[2] + acc0[3]*w2v[3];
  float p1 = acc1[0]*w1v[0] + acc1[1]*w1v[1] + acc1[2]*w1v[2] + acc1[3]*w1v[3];
  float q1 = acc1[0]*w2v[0] + acc1[1]*w2v[1] + acc1[2]*w2v[2] + acc1[3]*w2v[3];
  #pragma unroll
  for (int d = 1; d < 16; d <<= 1) {
    p0 += __shfl_xor(p0, d, 64); q0 += __shfl_xor(q0, d, 64);
    p1 += __shfl_xor(p1, d, 64); q1 += __shfl_xor(q1, d, 64);
  }
  if (cg == 0) {
    f1[row0] = p0 + b1[0]; f2[row0] = q0 + b2[0];
    f1[row1] = p1 + b1[0]; f2[row1] = q1 + b2[0];
  }
}

// ---------------------------------------------------------------------------
// K2a: partial ranks. Block (jt,kt) of 32x32: 256 j's vs 256 k's.
// k-values staged in 1KB LDS, read at wave-uniform address (broadcast, free).
// part[kt][j] = #{k in tile: f2[k]<f2[j] or (== and k<j)}
// ---------------------------------------------------------------------------
__global__ __launch_bounds__(256) void k_rankA(const float* __restrict__ f2,
                                               int* __restrict__ part) {
  __shared__ float lf2[256];
  const int t = threadIdx.x;
  const int jt = blockIdx.x & 31, kt = blockIdx.x >> 5;
  lf2[t] = f2[kt * 256 + t];
  const int j = jt * 256 + t;
  const float fj = f2[j];
  __syncthreads();
  const int k0 = kt * 256;
  int cnt = 0;
  #pragma unroll 8
  for (int kk = 0; kk < 256; ++kk) {
    const float v = lf2[kk];
    cnt += (v < fj || (v == fj && (k0 + kk) < j)) ? 1 : 0;
  }
  part[kt * N + j] = cnt;
}

// ---------------------------------------------------------------------------
// K2b: rank = sum of 32 partials (exact permutation); scatter sorted arrays.
// ---------------------------------------------------------------------------
__global__ __launch_bounds__(256) void k_rankB(
    const float* __restrict__ f2, const int* __restrict__ part,
    float* __restrict__ f2s, float* __restrict__ us, float* __restrict__ u2s,
    int* __restrict__ idxs) {
  const int j = blockIdx.x * 256 + threadIdx.x;
  int r = 0;
  #pragma unroll
  for (int kt = 0; kt < 32; ++kt) r += part[kt * N + j];
  const float v = f2[j];
  f2s[r]  = v;
  us[r]   = expf(v);
  u2s[r]  = expf(0.2f * v);
  idxs[r] = j;
}

// ---------------------------------------------------------------------------
// Scan phase A: per-chunk sums (both weightings + scalars), double accum.
// Layout: c = lane (so the sf row read is one contiguous 256B wave-load;
// idxs[pos] is lane-uniform). 256 blocks x 512 thr, chunk = 32 positions.
// ---------------------------------------------------------------------------
__global__ __launch_bounds__(512) void k_scanA(
    const float* __restrict__ us, const float* __restrict__ u2s,
    const int* __restrict__ idxs, const float* __restrict__ sf,
    float* __restrict__ chSumP, float* __restrict__ chSumN) {
  const int t = threadIdx.x;
  const int c = t & 63, pg = t >> 6;
  const int chunk = blockIdx.x;
  const int p0 = chunk * CHSZ + pg * 4;
  double aP = 0.0, aN = 0.0, sP = 0.0, sN = 0.0;
  #pragma unroll
  for (int i = 0; i < 4; ++i) {
    const int pos = p0 + i;
    const int idx = idxs[pos];
    const float w1 = us[pos], w2 = u2s[pos];
    const float s = sf[(size_t)idx * D + c];
    aP += (double)w1 * (double)s;
    aN += (double)w2 * (double)s;
    sP += (double)w1;
    sN += (double)w2;
  }
  __shared__ double redP[8][66], redN[8][66];
  redP[pg][c] = aP; redN[pg][c] = aN;
  if (c == 0) { redP[pg][64] = sP; redN[pg][64] = sN; }
  __syncthreads();
  if (t < NCOMP) {
    double tp = 0.0, tn = 0.0;
    #pragma unroll
    for (int q = 0; q < 8; ++q) { tp += redP[q][t]; tn += redN[q][t]; }
    chSumP[chunk * NCOMP + t] = (float)tp;
    chSumN[chunk * NCOMP + t] = (float)tn;
  }
}

// ---------------------------------------------------------------------------
// Scan phase B: single block. Exclusive prefix of chunk sums per component
// (serial over 256 chunks, in LDS, double accum); totals at tail slot.
// Also writes boundary rows (prefN[0]=0, sufP[N]=0).
// ---------------------------------------------------------------------------
__global__ __launch_bounds__(512) void k_scanB(
    const float* __restrict__ chSumP, const float* __restrict__ chSumN,
    float* __restrict__ chOffP, float* __restrict__ chOffN,
    float* __restrict__ prefNv, float* __restrict__ prefNs,
    float* __restrict__ sufPv, float* __restrict__ sufPs) {
  __shared__ float lp[NCHUNK * NCOMP], ln[NCHUNK * NCOMP];  // 2x65KB
  const int t = threadIdx.x;
  for (int i = t; i < NCHUNK * NCOMP; i += 512) { lp[i] = chSumP[i]; ln[i] = chSumN[i]; }
  __syncthreads();
  if (t < NCOMP) {
    double run = 0.0;
    for (int ch = 0; ch < NCHUNK; ++ch) {
      chOffN[ch * NCOMP + t] = (float)run;
      run += (double)ln[ch * NCOMP + t];
    }
    chOffN[NCHUNK * NCOMP + t] = (float)run;
  } else if (t < 2 * NCOMP) {
    const int comp = t - NCOMP;
    double run = 0.0;
    for (int ch = 0; ch < NCHUNK; ++ch) {
      chOffP[ch * NCOMP + comp] = (float)run;
      run += (double)lp[ch * NCOMP + comp];
    }
    chOffP[NCHUNK * NCOMP + comp] = (float)run;
  } else if (t >= 192 && t < 256) {
    prefNv[t - 192] = 0.f;
  } else if (t >= 256 && t < 320) {
    sufPv[(size_t)N * D + (t - 256)] = 0.f;
  } else if (t == 320) {
    prefNs[0] = 0.f;
  } else if (t == 321) {
    sufPs[N] = 0.f;
  }
}

// ---------------------------------------------------------------------------
// Scan phase C: emit. prefN inclusive prefix; sufP = total - exclusive prefix
// (double arithmetic; cancellation bounded ~1e-4 abs on 2e4-scale sums).
// ---------------------------------------------------------------------------
__global__ __launch_bounds__(512) void k_scanC(
    const float* __restrict__ us, const float* __restrict__ u2s,
    const int* __restrict__ idxs, const float* __restrict__ sf,
    const float* __restrict__ chOffP, const float* __restrict__ chOffN,
    float* __restrict__ prefNv, float* __restrict__ prefNs,
    float* __restrict__ sufPv, float* __restrict__ sufPs) {
  const int t = threadIdx.x;
  const int c = t & 63, pg = t >> 6;
  const int chunk = blockIdx.x;
  const int p0 = chunk * CHSZ + pg * 4;
  float w1v[4], w2v[4];
  double prodP[4], prodN[4];
  #pragma unroll
  for (int i = 0; i < 4; ++i) {
    const int pos = p0 + i;
    const int idx = idxs[pos];
    w1v[i] = us[pos]; w2v[i] = u2s[pos];
    const float s = sf[(size_t)idx * D + c];
    prodP[i] = (double)w1v[i] * (double)s;
    prodN[i] = (double)w2v[i] * (double)s;
  }
  __shared__ double redP[8][66], redN[8][66];
  redP[pg][c] = prodP[0] + prodP[1] + prodP[2] + prodP[3];
  redN[pg][c] = prodN[0] + prodN[1] + prodN[2] + prodN[3];
  if (c == 0) {
    redP[pg][64] = (double)w1v[0] + w1v[1] + w1v[2] + w1v[3];
    redN[pg][64] = (double)w2v[0] + w2v[1] + w2v[2] + w2v[3];
  }
  __syncthreads();
  double eP = 0.0, eN = 0.0;
  for (int q = 0; q < pg; ++q) { eP += redP[q][c]; eN += redN[q][c]; }
  double runP = (double)chOffP[chunk * NCOMP + c] + eP;
  double runN = (double)chOffN[chunk * NCOMP + c] + eN;
  const double totPv = (double)chOffP[NCHUNK * NCOMP + c];
  #pragma unroll
  for (int i = 0; i < 4; ++i) {
    const int pos = p0 + i;
    sufPv[(size_t)pos * D + c] = (float)(totPv - runP);   // runP = sum over p<pos
    runP += prodP[i];
    runN += prodN[i];
    prefNv[(size_t)(pos + 1) * D + c] = (float)runN;
  }
  if (c == 0) {
    double ePs = 0.0, eNs = 0.0;
    for (int q = 0; q < pg; ++q) { ePs += redP[q][64]; eNs += redN[q][64]; }
    double runPs = (double)chOffP[chunk * NCOMP + 64] + ePs;
    double runNs = (double)chOffN[chunk * NCOMP + 64] + eNs;
    const double totPs = (double)chOffP[NCHUNK * NCOMP + 64];
    #pragma unroll
    for (int i = 0; i < 4; ++i) {
      const int pos = p0 + i;
      sufPs[pos] = (float)(totPs - runPs);
      runPs += (double)w1v[i];
      runNs += (double)w2v[i];
      prefNs[pos + 1] = (float)runNs;
    }
  }
}

// ---------------------------------------------------------------------------
// K5: one output element per thread; per-wave-uniform binary search on
// L2-resident f2s (13 broadcast loads), 2048 blocks for TLP.
// ---------------------------------------------------------------------------
__global__ __launch_bounds__(256) void k_out(
    const float* __restrict__ f1, const float* __restrict__ f2s,
    const float* __restrict__ prefNv, const float* __restrict__ prefNs,
    const float* __restrict__ sufPv, const float* __restrict__ sufPs,
    const float* __restrict__ bias, float* __restrict__ out) {
  const int t = threadIdx.x;
  const int c = t & 63;
  const int row = blockIdx.x * 4 + (t >> 6);
  const float a = f1[row];
  const float tv = -a;
  int lo = 0, hi = N;
  while (lo < hi) {
    int mid = (lo + hi) >> 1;
    if (f2s[mid] <= tv) lo = mid + 1; else hi = mid;
  }
  const int k = lo;  // #{f2 <= -a} = N-branch size
  const float ea = expf(a), ea2 = expf(0.2f * a);
  const float den = ea * sufPs[k] + ea2 * prefNs[k];
  const float num = ea * sufPv[(size_t)k * D + c] + ea2 * prefNv[(size_t)k * D + c];
  out[(size_t)row * D + c] = num / den + bias[c];
}

extern "C" void kernel_launch(void* const* d_in, const int* in_sizes, int n_in,
                              void* d_out, int out_size, void* d_ws, size_t ws_size,
                              hipStream_t stream) {
  const float* seq  = (const float*)d_in[0];
  const float* W0   = (const float*)d_in[1];
  const float* w1   = (const float*)d_in[2];
  const float* b1   = (const float*)d_in[3];
  const float* w2   = (const float*)d_in[4];
  const float* b2   = (const float*)d_in[5];
  const float* bias = (const float*)d_in[6];
  float* out = (float*)d_out;

  float* ws   = (float*)d_ws;
  float* sf   = ws;                                    // N*D
  float* f1   = sf + (size_t)N * D;                    // N
  float* f2   = f1 + N;                                // N
  float* f2s  = f2 + N;                                // N
  float* us   = f2s + N;                               // N
  float* u2s  = us + N;                                // N
  int*   idxs = (int*)(u2s + N);                       // N
  int*   part = idxs + N;                              // 32*N
  float* prefNv = (float*)(part + 32 * N);             // (N+1)*D
  float* sufPv  = prefNv + (size_t)(N + 1) * D;        // (N+1)*D
  float* prefNs = sufPv + (size_t)(N + 1) * D;         // N+1
  float* sufPs  = prefNs + (N + 1);                    // N+1
  float* chSumP = sufPs + (N + 1);                     // (NCHUNK+1)*NCOMP
  float* chSumN = chSumP + (NCHUNK + 1) * NCOMP;
  float* chOffP = chSumN + (NCHUNK + 1) * NCOMP;
  float* chOffN = chOffP + (NCHUNK + 1) * NCOMP;
  // total ~7.8 MB of d_ws

  k_proj<<<N / 32, 256, 0, stream>>>(seq, W0, w1, b1, w2, b2, sf, f1, f2);
  k_rankA<<<1024, 256, 0, stream>>>(f2, part);
  k_rankB<<<32, 256, 0, stream>>>(f2, part, f2s, us, u2s, idxs);
  k_scanA<<<NCHUNK, 512, 0, stream>>>(us, u2s, idxs, sf, chSumP, chSumN);
  k_scanB<<<1, 512, 0, stream>>>(chSumP, chSumN, chOffP, chOffN,
                                 prefNv, prefNs, sufPv, sufPs);
  k_scanC<<<NCHUNK, 512, 0, stream>>>(us, u2s, idxs, sf, chOffP, chOffN,
                                      prefNv, prefNs, sufPv, sufPs);
  k_out<<<N / 4, 256, 0, stream>>>(f1, f2s, prefNv, prefNs, sufPv, sufPs, bias, out);
}

// Round 4
// 54.343 us; speedup vs baseline: 1.8834x; 1.0114x over previous
//
#include <hip/hip_runtime.h>

#define N 8192
#define F 256
#define D 64
#define CHSZ 16      // positions per scan chunk
#define NCHUNK 512   // N / CHSZ
#define NCOMP 65     // 64 vector components + 1 scalar

// monotone key: float order -> unsigned order, tie-broken by index j (13 bits)
__device__ __forceinline__ unsigned long long monokey(float f, int j) {
  unsigned int b = __float_as_uint(f);
  b ^= ((unsigned int)((int)b >> 31)) | 0x80000000u;
  return ((unsigned long long)b << 13) | (unsigned int)j;
}

// ---------------------------------------------------------------------------
// K1: sf = seq@W0 (fp32), f1 = sf@w1+b1, f2 = sf@w2+b2, gkey = monokey(f2,row)
// 256 blocks x 256 thr, 32 rows/block. Structurally unchanged control.
// ---------------------------------------------------------------------------
__global__ __launch_bounds__(256) void k_proj(
    const float* __restrict__ seq, const float* __restrict__ W0,
    const float* __restrict__ w1, const float* __restrict__ b1,
    const float* __restrict__ w2, const float* __restrict__ b2,
    float* __restrict__ sf, float* __restrict__ f1, float* __restrict__ f2,
    unsigned long long* __restrict__ gkey) {
  __shared__ __align__(16) float lw0[F * D];      // 64 KB
  __shared__ __align__(16) float srow[32 * 260];  // 33.3 KB padded
  const int t = threadIdx.x;
  {
    const float4* g = (const float4*)W0;
    float4* l = (float4*)lw0;
    #pragma unroll
    for (int i = 0; i < 16; ++i) l[t + i * 256] = g[t + i * 256];
  }
  const int base = blockIdx.x * 32;
  {
    const float4* g = (const float4*)(seq + (size_t)base * F);
    #pragma unroll
    for (int i = 0; i < 8; ++i) {
      int idx = t + i * 256;
      int r = idx >> 6, c4 = idx & 63;
      *(float4*)(srow + r * 260 + c4 * 4) = g[idx];
    }
  }
  __syncthreads();
  const int cg = t & 15, rg = t >> 4;
  const int r0 = rg * 2;
  float acc0[4] = {0.f, 0.f, 0.f, 0.f}, acc1[4] = {0.f, 0.f, 0.f, 0.f};
  const float* s0 = srow + r0 * 260;
  const float* s1 = s0 + 260;
  const float* wb = lw0 + cg * 4;
  #pragma unroll 4
  for (int k = 0; k < F; k += 4) {
    float a0[4], a1[4];
    *(float4*)a0 = *(const float4*)(s0 + k);
    *(float4*)a1 = *(const float4*)(s1 + k);
    #pragma unroll
    for (int m = 0; m < 4; ++m) {
      float4 w = *(const float4*)(wb + (k + m) * D);
      acc0[0] += a0[m] * w.x; acc0[1] += a0[m] * w.y;
      acc0[2] += a0[m] * w.z; acc0[3] += a0[m] * w.w;
      acc1[0] += a1[m] * w.x; acc1[1] += a1[m] * w.y;
      acc1[2] += a1[m] * w.z; acc1[3] += a1[m] * w.w;
    }
  }
  const int row0 = base + r0, row1 = row0 + 1;
  *(float4*)(sf + (size_t)row0 * D + cg * 4) = make_float4(acc0[0], acc0[1], acc0[2], acc0[3]);
  *(float4*)(sf + (size_t)row1 * D + cg * 4) = make_float4(acc1[0], acc1[1], acc1[2], acc1[3]);
  float w1v[4], w2v[4];
  *(float4*)w1v = *(const float4*)(w1 + cg * 4);
  *(float4*)w2v = *(const float4*)(w2 + cg * 4);
  float p0 = acc0[0]*w1v[0] + acc0[1]*w1v[1] + acc0[2]*w1v[2] + acc0[3]*w1v[3];
  float q0 = acc0[0]*w2v[0] + acc0[1]*w2v[1] + acc0[2]*w2v[2] + acc0[3]*w2v[3];
  float p1 = acc1[0]*w1v[0] + acc1[1]*w1v[1] + acc1[2]*w1v[2] + acc1[3]*w1v[3];
  float q1 = acc1[0]*w2v[0] + acc1[1]*w2v[1] + acc1[2]*w2v[2] + acc1[3]*w2v[3];
  #pragma unroll
  for (int d = 1; d < 16; d <<= 1) {
    p0 += __shfl_xor(p0, d, 64); q0 += __shfl_xor(q0, d, 64);
    p1 += __shfl_xor(p1, d, 64); q1 += __shfl_xor(q1, d, 64);
  }
  if (cg == 0) {
    const float f1a = p0 + b1[0], f2a = q0 + b2[0];
    const float f1b = p1 + b1[0], f2b = q1 + b2[0];
    f1[row0] = f1a; f2[row0] = f2a; gkey[row0] = monokey(f2a, row0);
    f1[row1] = f1b; f2[row1] = f2b; gkey[row1] = monokey(f2b, row1);
  }
}

// ---------------------------------------------------------------------------
// K2a: partial ranks via u64 key compares. Block (jt,kt): 256 j x 256 k.
// k-keys staged in 2KB LDS, wave-uniform broadcast reads.
// ---------------------------------------------------------------------------
__global__ __launch_bounds__(256) void k_rankA(
    const unsigned long long* __restrict__ gkey, int* __restrict__ part) {
  __shared__ unsigned long long lk[256];
  const int t = threadIdx.x;
  const int jt = blockIdx.x & 31, kt = blockIdx.x >> 5;
  lk[t] = gkey[kt * 256 + t];
  const int j = jt * 256 + t;
  const unsigned long long kj = gkey[j];
  __syncthreads();
  int cnt = 0;
  #pragma unroll 8
  for (int kk = 0; kk < 256; ++kk) cnt += (lk[kk] < kj) ? 1 : 0;
  part[kt * N + j] = cnt;
}

// ---------------------------------------------------------------------------
// K2b: rank = sum of 32 partials (exact permutation); scatter f2s + idxs.
// ---------------------------------------------------------------------------
__global__ __launch_bounds__(256) void k_rankB(
    const float* __restrict__ f2, const int* __restrict__ part,
    float* __restrict__ f2s, int* __restrict__ idxs) {
  const int j = blockIdx.x * 256 + threadIdx.x;
  int r = 0;
  #pragma unroll
  for (int kt = 0; kt < 32; ++kt) r += part[kt * N + j];
  f2s[r]  = f2[j];
  idxs[r] = j;
}

// ---------------------------------------------------------------------------
// K3: fused chunk-sums + cross-chunk exclusive prefix.
// 130 blocks: w = bid/65 (0:P weight e^f2, 1:N weight e^{0.2 f2}), c = bid%65
// (64 = scalar comp). 512 thr; thread=chunk sums its 16 positions (double),
// block-wide shfl scan -> chOff[ch] (exclusive), chOff[NCHUNK] = total.
// ---------------------------------------------------------------------------
__global__ __launch_bounds__(512) void k_scanAB(
    const float* __restrict__ f2s, const int* __restrict__ idxs,
    const float* __restrict__ sf,
    float* __restrict__ chOffP, float* __restrict__ chOffN) {
  const int t = threadIdx.x;
  const int w = blockIdx.x / NCOMP;
  const int c = blockIdx.x % NCOMP;
  const float wmul = w ? 0.2f : 1.0f;
  const int base = t * CHSZ;
  double sum = 0.0;
  #pragma unroll 4
  for (int i = 0; i < CHSZ; ++i) {
    const int pos = base + i;
    const float fv = f2s[pos];
    const float wv = expf(wmul * fv);
    const float s = (c < 64) ? sf[(size_t)idxs[pos] * D + c] : 1.0f;
    sum += (double)wv * (double)s;
  }
  // block scan (8 waves)
  const int wid = t >> 6, lane = t & 63;
  double x = sum;
  #pragma unroll
  for (int d = 1; d < 64; d <<= 1) {
    double n = __shfl_up(x, d, 64);
    if (lane >= d) x += n;
  }
  __shared__ double wt[8];
  if (lane == 63) wt[wid] = x;
  __syncthreads();
  double add = 0.0;
  for (int q = 0; q < wid; ++q) add += wt[q];
  double tot = 0.0;
  #pragma unroll
  for (int q = 0; q < 8; ++q) tot += wt[q];
  float* dst = w ? chOffN : chOffP;
  dst[(size_t)t * NCOMP + c] = (float)(add + x - sum);  // exclusive prefix
  if (t == 0) dst[(size_t)NCHUNK * NCOMP + c] = (float)tot;
}

// ---------------------------------------------------------------------------
// K4: output. Per row (1 wave): binary search k on f2s; reconstruct
// prefN(k)/sufP(k) = chunk offset + on-the-fly partial over <=16 positions
// (wave-uniform loop; sf row read is a coalesced 256B load).
// ---------------------------------------------------------------------------
__global__ __launch_bounds__(256) void k_outF(
    const float* __restrict__ f1, const float* __restrict__ f2s,
    const int* __restrict__ idxs, const float* __restrict__ sf,
    const float* __restrict__ chOffP, const float* __restrict__ chOffN,
    const float* __restrict__ bias, float* __restrict__ out) {
  const int t = threadIdx.x;
  const int c = t & 63;
  const int row = blockIdx.x * 4 + (t >> 6);
  const float a = f1[row];
  const float tv = -a;
  int lo = 0, hi = N;
  #pragma unroll
  for (int it = 0; it < 13; ++it) {
    int mid = (lo + hi) >> 1;
    if (f2s[mid] <= tv) lo = mid + 1; else hi = mid;
  }
  const int k = lo;           // #{f2 <= -a}; k in [0, N]
  const int ch = k >> 4;      // CHSZ = 16; k==N -> ch==NCHUNK (totals row, empty loop)
  double pP = chOffP[(size_t)ch * NCOMP + c];
  double sP = chOffP[(size_t)ch * NCOMP + 64];
  double pN = chOffN[(size_t)ch * NCOMP + c];
  double sN = chOffN[(size_t)ch * NCOMP + 64];
  const double tpv = chOffP[(size_t)NCHUNK * NCOMP + c];
  const double tps = chOffP[(size_t)NCHUNK * NCOMP + 64];
  for (int pos = ch * CHSZ; pos < k; ++pos) {
    const float fv = f2s[pos];
    const float s = sf[(size_t)idxs[pos] * D + c];
    const float e1 = expf(fv), e2 = expf(0.2f * fv);
    pP += (double)e1 * s; sP += (double)e1;
    pN += (double)e2 * s; sN += (double)e2;
  }
  const float ea = expf(a), ea2 = expf(0.2f * a);
  const double num = (double)ea * (tpv - pP) + (double)ea2 * pN;
  const double den = (double)ea * (tps - sP) + (double)ea2 * sN;
  out[(size_t)row * D + c] = (float)(num / den) + bias[c];
}

extern "C" void kernel_launch(void* const* d_in, const int* in_sizes, int n_in,
                              void* d_out, int out_size, void* d_ws, size_t ws_size,
                              hipStream_t stream) {
  const float* seq  = (const float*)d_in[0];
  const float* W0   = (const float*)d_in[1];
  const float* w1   = (const float*)d_in[2];
  const float* b1   = (const float*)d_in[3];
  const float* w2   = (const float*)d_in[4];
  const float* b2   = (const float*)d_in[5];
  const float* bias = (const float*)d_in[6];
  float* out = (float*)d_out;

  float* ws   = (float*)d_ws;
  float* sf   = ws;                                       // N*D
  float* f1   = sf + (size_t)N * D;                       // N
  float* f2   = f1 + N;                                   // N
  unsigned long long* gkey = (unsigned long long*)(f2 + N); // N (8B aligned)
  int*   part = (int*)(gkey + N);                         // 32*N
  float* f2s  = (float*)(part + 32 * N);                  // N
  int*   idxs = (int*)(f2s + N);                          // N
  float* chOffP = (float*)(idxs + N);                     // (NCHUNK+1)*NCOMP
  float* chOffN = chOffP + (size_t)(NCHUNK + 1) * NCOMP;  // (NCHUNK+1)*NCOMP
  // total ~3.4 MB of d_ws

  k_proj<<<N / 32, 256, 0, stream>>>(seq, W0, w1, b1, w2, b2, sf, f1, f2, gkey);
  k_rankA<<<1024, 256, 0, stream>>>(gkey, part);
  k_rankB<<<32, 256, 0, stream>>>(f2, part, f2s, idxs);
  k_scanAB<<<2 * NCOMP, 512, 0, stream>>>(f2s, idxs, sf, chOffP, chOffN);
  k_outF<<<N / 4, 256, 0, stream>>>(f1, f2s, idxs, sf, chOffP, chOffN, bias, out);
}

// Round 5
// 53.740 us; speedup vs baseline: 1.9045x; 1.0112x over previous
//
#include <hip/hip_runtime.h>

#define N 8192
#define F 256
#define D 64
#define CHSZ 16      // positions per scan chunk
#define NCHUNK 512   // N / CHSZ
#define NCOMP 65     // 64 vector components + 1 scalar

// monotone key: float order -> unsigned order, tie-broken by index j (13 bits)
__device__ __forceinline__ unsigned long long monokey(float f, int j) {
  unsigned int b = __float_as_uint(f);
  b ^= ((unsigned int)((int)b >> 31)) | 0x80000000u;
  return ((unsigned long long)b << 13) | (unsigned int)j;
}
// inverse of the monotone 32-bit map (key>>13 -> float bits)
__device__ __forceinline__ float monoinv(unsigned long long key) {
  unsigned int m = (unsigned int)(key >> 13);
  unsigned int b = (m & 0x80000000u) ? (m ^ 0x80000000u) : ~m;
  return __uint_as_float(b);
}

// ---------------------------------------------------------------------------
// K1: sf = seq@W0 (fp32), f1 = sf@w1+b1, gkey = monokey(sf@w2+b2, row)
// 256 blocks x 256 thr, 32 rows/block. W0 (64KB) + padded seq rows in LDS.
// ---------------------------------------------------------------------------
__global__ __launch_bounds__(256) void k_proj(
    const float* __restrict__ seq, const float* __restrict__ W0,
    const float* __restrict__ w1, const float* __restrict__ b1,
    const float* __restrict__ w2, const float* __restrict__ b2,
    float* __restrict__ sf, float* __restrict__ f1,
    unsigned long long* __restrict__ gkey) {
  __shared__ __align__(16) float lw0[F * D];      // 64 KB
  __shared__ __align__(16) float srow[32 * 260];  // 33.3 KB padded
  const int t = threadIdx.x;
  {
    const float4* g = (const float4*)W0;
    float4* l = (float4*)lw0;
    #pragma unroll
    for (int i = 0; i < 16; ++i) l[t + i * 256] = g[t + i * 256];
  }
  const int base = blockIdx.x * 32;
  {
    const float4* g = (const float4*)(seq + (size_t)base * F);
    #pragma unroll
    for (int i = 0; i < 8; ++i) {
      int idx = t + i * 256;
      int r = idx >> 6, c4 = idx & 63;
      *(float4*)(srow + r * 260 + c4 * 4) = g[idx];
    }
  }
  __syncthreads();
  const int cg = t & 15, rg = t >> 4;
  const int r0 = rg * 2;
  float acc0[4] = {0.f, 0.f, 0.f, 0.f}, acc1[4] = {0.f, 0.f, 0.f, 0.f};
  const float* s0 = srow + r0 * 260;
  const float* s1 = s0 + 260;
  const float* wb = lw0 + cg * 4;
  #pragma unroll 4
  for (int k = 0; k < F; k += 4) {
    float a0[4], a1[4];
    *(float4*)a0 = *(const float4*)(s0 + k);
    *(float4*)a1 = *(const float4*)(s1 + k);
    #pragma unroll
    for (int m = 0; m < 4; ++m) {
      float4 w = *(const float4*)(wb + (k + m) * D);
      acc0[0] += a0[m] * w.x; acc0[1] += a0[m] * w.y;
      acc0[2] += a0[m] * w.z; acc0[3] += a0[m] * w.w;
      acc1[0] += a1[m] * w.x; acc1[1] += a1[m] * w.y;
      acc1[2] += a1[m] * w.z; acc1[3] += a1[m] * w.w;
    }
  }
  const int row0 = base + r0, row1 = row0 + 1;
  *(float4*)(sf + (size_t)row0 * D + cg * 4) = make_float4(acc0[0], acc0[1], acc0[2], acc0[3]);
  *(float4*)(sf + (size_t)row1 * D + cg * 4) = make_float4(acc1[0], acc1[1], acc1[2], acc1[3]);
  float w1v[4], w2v[4];
  *(float4*)w1v = *(const float4*)(w1 + cg * 4);
  *(float4*)w2v = *(const float4*)(w2 + cg * 4);
  float p0 = acc0[0]*w1v[0] + acc0[1]*w1v[1] + acc0[2]*w1v[2] + acc0[3]*w1v[3];
  float q0 = acc0[0]*w2v[0] + acc0[1]*w2v[1] + acc0[2]*w2v[2] + acc0[3]*w2v[3];
  float p1 = acc1[0]*w1v[0] + acc1[1]*w1v[1] + acc1[2]*w1v[2] + acc1[3]*w1v[3];
  float q1 = acc1[0]*w2v[0] + acc1[1]*w2v[1] + acc1[2]*w2v[2] + acc1[3]*w2v[3];
  #pragma unroll
  for (int d = 1; d < 16; d <<= 1) {
    p0 += __shfl_xor(p0, d, 64); q0 += __shfl_xor(q0, d, 64);
    p1 += __shfl_xor(p1, d, 64); q1 += __shfl_xor(q1, d, 64);
  }
  if (cg == 0) {
    const float f1a = p0 + b1[0], f2a = q0 + b2[0];
    const float f1b = p1 + b1[0], f2b = q1 + b2[0];
    f1[row0] = f1a; gkey[row0] = monokey(f2a, row0);
    f1[row1] = f1b; gkey[row1] = monokey(f2b, row1);
  }
}

// ---------------------------------------------------------------------------
// K2a: partial ranks via u64 key compares. Block (jt,kt): 256 j x 256 k.
// k-keys staged in 2KB LDS, wave-uniform broadcast reads.
// ---------------------------------------------------------------------------
__global__ __launch_bounds__(256) void k_rankA(
    const unsigned long long* __restrict__ gkey, int* __restrict__ part) {
  __shared__ unsigned long long lk[256];
  const int t = threadIdx.x;
  const int jt = blockIdx.x & 31, kt = blockIdx.x >> 5;
  lk[t] = gkey[kt * 256 + t];
  const int j = jt * 256 + t;
  const unsigned long long kj = gkey[j];
  __syncthreads();
  int cnt = 0;
  #pragma unroll 8
  for (int kk = 0; kk < 256; ++kk) cnt += (lk[kk] < kj) ? 1 : 0;
  part[kt * N + j] = cnt;
}

// ---------------------------------------------------------------------------
// K2b: rank = sum of 32 partials (exact permutation); scatter f2s + idxs.
// f2 value reconstructed from the monotone key (f2 buffer eliminated).
// ---------------------------------------------------------------------------
__global__ __launch_bounds__(256) void k_rankB(
    const unsigned long long* __restrict__ gkey, const int* __restrict__ part,
    float* __restrict__ f2s, int* __restrict__ idxs) {
  const int j = blockIdx.x * 256 + threadIdx.x;
  int r = 0;
  #pragma unroll
  for (int kt = 0; kt < 32; ++kt) r += part[kt * N + j];
  f2s[r]  = monoinv(gkey[j]);
  idxs[r] = j;
}

// ---------------------------------------------------------------------------
// K3: fused chunk-sums + cross-chunk exclusive prefix.
// 130 blocks: w = bid/65 (0:P weight e^f2, 1:N weight e^{0.2 f2}), c = bid%65
// (64 = scalar comp). 512 thr; thread=chunk sums its 16 positions (double),
// block-wide shfl scan -> chOff[ch] (exclusive), chOff[NCHUNK] = total.
// ---------------------------------------------------------------------------
__global__ __launch_bounds__(512) void k_scanAB(
    const float* __restrict__ f2s, const int* __restrict__ idxs,
    const float* __restrict__ sf,
    float* __restrict__ chOffP, float* __restrict__ chOffN) {
  const int t = threadIdx.x;
  const int w = blockIdx.x / NCOMP;
  const int c = blockIdx.x % NCOMP;
  const float wmul = w ? 0.2f : 1.0f;
  const int base = t * CHSZ;
  double sum = 0.0;
  #pragma unroll 4
  for (int i = 0; i < CHSZ; ++i) {
    const int pos = base + i;
    const float fv = f2s[pos];
    const float wv = expf(wmul * fv);
    const float s = (c < 64) ? sf[(size_t)idxs[pos] * D + c] : 1.0f;
    sum += (double)wv * (double)s;
  }
  const int wid = t >> 6, lane = t & 63;
  double x = sum;
  #pragma unroll
  for (int d = 1; d < 64; d <<= 1) {
    double n = __shfl_up(x, d, 64);
    if (lane >= d) x += n;
  }
  __shared__ double wt[8];
  if (lane == 63) wt[wid] = x;
  __syncthreads();
  double add = 0.0;
  for (int q = 0; q < wid; ++q) add += wt[q];
  double tot = 0.0;
  #pragma unroll
  for (int q = 0; q < 8; ++q) tot += wt[q];
  float* dst = w ? chOffN : chOffP;
  dst[(size_t)t * NCOMP + c] = (float)(add + x - sum);  // exclusive prefix
  if (t == 0) dst[(size_t)NCHUNK * NCOMP + c] = (float)tot;
}

// ---------------------------------------------------------------------------
// K4: output. Per row (1 wave): exact binary search for k = #{f2 <= -f1[row]}
// (while-loop: the fixed-13-iteration version had a rare off-by-one when the
// final interval had size 1); reconstruct prefN(k)/sufP(k) from chunk offset
// + on-the-fly partial over <=16 positions (wave-uniform loop, coalesced
// 256B sf row reads).
// ---------------------------------------------------------------------------
__global__ __launch_bounds__(256) void k_outF(
    const float* __restrict__ f1, const float* __restrict__ f2s,
    const int* __restrict__ idxs, const float* __restrict__ sf,
    const float* __restrict__ chOffP, const float* __restrict__ chOffN,
    const float* __restrict__ bias, float* __restrict__ out) {
  const int t = threadIdx.x;
  const int c = t & 63;
  const int row = blockIdx.x * 4 + (t >> 6);
  const float a = f1[row];
  const float tv = -a;
  int lo = 0, hi = N;
  while (lo < hi) {
    int mid = (lo + hi) >> 1;
    if (f2s[mid] <= tv) lo = mid + 1; else hi = mid;
  }
  const int k = lo;           // #{f2 <= -a}; k in [0, N]
  const int ch = k >> 4;      // CHSZ = 16; k==N -> ch==NCHUNK (totals row, empty loop)
  double pP = chOffP[(size_t)ch * NCOMP + c];
  double sP = chOffP[(size_t)ch * NCOMP + 64];
  double pN = chOffN[(size_t)ch * NCOMP + c];
  double sN = chOffN[(size_t)ch * NCOMP + 64];
  const double tpv = chOffP[(size_t)NCHUNK * NCOMP + c];
  const double tps = chOffP[(size_t)NCHUNK * NCOMP + 64];
  for (int pos = ch * CHSZ; pos < k; ++pos) {
    const float fv = f2s[pos];
    const float s = sf[(size_t)idxs[pos] * D + c];
    const float e1 = expf(fv), e2 = expf(0.2f * fv);
    pP += (double)e1 * s; sP += (double)e1;
    pN += (double)e2 * s; sN += (double)e2;
  }
  const float ea = expf(a), ea2 = expf(0.2f * a);
  const double num = (double)ea * (tpv - pP) + (double)ea2 * pN;
  const double den = (double)ea * (tps - sP) + (double)ea2 * sN;
  out[(size_t)row * D + c] = (float)(num / den) + bias[c];
}

extern "C" void kernel_launch(void* const* d_in, const int* in_sizes, int n_in,
                              void* d_out, int out_size, void* d_ws, size_t ws_size,
                              hipStream_t stream) {
  const float* seq  = (const float*)d_in[0];
  const float* W0   = (const float*)d_in[1];
  const float* w1   = (const float*)d_in[2];
  const float* b1   = (const float*)d_in[3];
  const float* w2   = (const float*)d_in[4];
  const float* b2   = (const float*)d_in[5];
  const float* bias = (const float*)d_in[6];
  float* out = (float*)d_out;

  float* ws   = (float*)d_ws;
  float* sf   = ws;                                         // N*D
  float* f1   = sf + (size_t)N * D;                         // N
  unsigned long long* gkey = (unsigned long long*)(f1 + N); // N (8B aligned)
  int*   part = (int*)(gkey + N);                           // 32*N
  float* f2s  = (float*)(part + 32 * N);                    // N
  int*   idxs = (int*)(f2s + N);                            // N
  float* chOffP = (float*)(idxs + N);                       // (NCHUNK+1)*NCOMP
  float* chOffN = chOffP + (size_t)(NCHUNK + 1) * NCOMP;    // (NCHUNK+1)*NCOMP
  // total ~3.4 MB of d_ws

  k_proj<<<N / 32, 256, 0, stream>>>(seq, W0, w1, b1, w2, b2, sf, f1, gkey);
  k_rankA<<<1024, 256, 0, stream>>>(gkey, part);
  k_rankB<<<32, 256, 0, stream>>>(gkey, part, f2s, idxs);
  k_scanAB<<<2 * NCOMP, 512, 0, stream>>>(f2s, idxs, sf, chOffP, chOffN);
  k_outF<<<N / 4, 256, 0, stream>>>(f1, f2s, idxs, sf, chOffP, chOffN, bias, out);
}